// Round 5
// baseline (324.860 us; speedup 1.0000x reference)
//
#include <hip/hip_runtime.h>
#include <hip/hip_bf16.h>

typedef __attribute__((ext_vector_type(8))) short short8;
typedef __attribute__((ext_vector_type(4))) float f32x4;
typedef __attribute__((ext_vector_type(16))) float f32x16;
typedef __hip_bfloat16 bf16;

#define NH 16
#define DK 64
#define SEQ 2048
#define DIM 1024
#define NEG_INF_F (-1.0e9f)

static __device__ __forceinline__ unsigned short f2bf_bits(float f) {
    bf16 t = __float2bfloat16(f);
    return *reinterpret_cast<unsigned short*>(&t);
}

// ---------------- fused convert f32 -> bf16 for q,k,v ----------------
__global__ void cvt_all_kernel(const float* __restrict__ q, const float* __restrict__ k,
                               const float* __restrict__ v, bf16* __restrict__ qb,
                               bf16* __restrict__ kb, bf16* __restrict__ vb) {
    const int N4 = 2 * SEQ * DIM / 4;   // 1,048,576 float4 per tensor
    int i = blockIdx.x * blockDim.x + threadIdx.x;
    int sel = i / N4, j = i - sel * N4;
    const float* in = (sel == 0) ? q : (sel == 1) ? k : v;
    bf16* out = (sel == 0) ? qb : (sel == 1) ? kb : vb;
    float4 x = reinterpret_cast<const float4*>(in)[j];
    ushort4 u;
    u.x = f2bf_bits(x.x);
    u.y = f2bf_bits(x.y);
    u.z = f2bf_bits(x.z);
    u.w = f2bf_bits(x.w);
    reinterpret_cast<ushort4*>(out)[j] = u;
}

// ---------------- fused W (K x N) f32 -> Wt (N x K) bf16 for 4 weights ----------------
__global__ void transpose_cvt_kernel(const float* __restrict__ Wq, const float* __restrict__ Wk,
                                     const float* __restrict__ Wv, const float* __restrict__ Wo,
                                     bf16* __restrict__ Wqt, bf16* __restrict__ Wkt,
                                     bf16* __restrict__ Wvt, bf16* __restrict__ Wot) {
    __shared__ float t[32][33];
    const int z = blockIdx.z;
    const float* W = (z == 0) ? Wq : (z == 1) ? Wk : (z == 2) ? Wv : Wo;
    bf16* Wt = (z == 0) ? Wqt : (z == 1) ? Wkt : (z == 2) ? Wvt : Wot;
    int n0 = blockIdx.x * 32, k0 = blockIdx.y * 32;
    int tx = threadIdx.x, ty = threadIdx.y;   // 32 x 8
#pragma unroll
    for (int i = 0; i < 4; i++)
        t[ty + i * 8][tx] = W[(size_t)(k0 + ty + i * 8) * DIM + n0 + tx];
    __syncthreads();
#pragma unroll
    for (int i = 0; i < 4; i++)
        Wt[(size_t)(n0 + ty + i * 8) * DIM + k0 + tx] = __float2bfloat16(t[tx][ty + i * 8]);
}

// ---------------- fused QKV projection GEMM (unchanged structure) ----------------
__global__ __launch_bounds__(256) void qkv_gemm_kernel(
    const bf16* __restrict__ qb, const bf16* __restrict__ kb, const bf16* __restrict__ vb,
    const bf16* __restrict__ Wcat,
    const float* __restrict__ bq, const float* __restrict__ bk, const float* __restrict__ bv,
    bf16* __restrict__ Qh, bf16* __restrict__ Kh, bf16* __restrict__ Vt)
{
    __shared__ __align__(16) bf16 Xs[2][128 * 40];
    __shared__ __align__(16) bf16 Ws[2][128 * 40];
    const int tid = threadIdx.x;
    const int w = tid >> 6, l = tid & 63;
    const int l15 = l & 15, l4 = l >> 4;
    const int m0 = blockIdx.x * 128;
    const int by = blockIdx.y;
    const int proj = by >> 3;
    const int n0 = (by & 7) * 128;
    const bf16* X = (proj == 0) ? qb : (proj == 1) ? kb : vb;
    const bf16* Wt = Wcat + (size_t)proj * DIM * DIM + (size_t)n0 * DIM;
    const float* bias = (proj == 0) ? bq : (proj == 1) ? bk : bv;
    const int wr = w >> 1, wc = w & 1;
    f32x4 acc[4][4] = {};

    const int c0 = tid, c1 = 256 + tid;
    const int r0 = c0 >> 2, ch0 = c0 & 3;
    const int r1 = c1 >> 2, ch1 = c1 & 3;
    const bf16* Xp = X + (size_t)m0 * DIM;

    short8 x0 = *reinterpret_cast<const short8*>(&Xp[(size_t)r0 * DIM + ch0 * 8]);
    short8 x1 = *reinterpret_cast<const short8*>(&Xp[(size_t)r1 * DIM + ch1 * 8]);
    short8 w0 = *reinterpret_cast<const short8*>(&Wt[(size_t)r0 * DIM + ch0 * 8]);
    short8 w1 = *reinterpret_cast<const short8*>(&Wt[(size_t)r1 * DIM + ch1 * 8]);
    *reinterpret_cast<short8*>(&Xs[0][r0 * 40 + ch0 * 8]) = x0;
    *reinterpret_cast<short8*>(&Xs[0][r1 * 40 + ch1 * 8]) = x1;
    *reinterpret_cast<short8*>(&Ws[0][r0 * 40 + ch0 * 8]) = w0;
    *reinterpret_cast<short8*>(&Ws[0][r1 * 40 + ch1 * 8]) = w1;
    __syncthreads();

    int cur = 0;
    for (int k0 = 0; k0 < DIM; k0 += 32) {
        const bool more = (k0 + 32) < DIM;
        short8 nx0, nx1, nw0, nw1;
        if (more) {
            nx0 = *reinterpret_cast<const short8*>(&Xp[(size_t)r0 * DIM + k0 + 32 + ch0 * 8]);
            nx1 = *reinterpret_cast<const short8*>(&Xp[(size_t)r1 * DIM + k0 + 32 + ch1 * 8]);
            nw0 = *reinterpret_cast<const short8*>(&Wt[(size_t)r0 * DIM + k0 + 32 + ch0 * 8]);
            nw1 = *reinterpret_cast<const short8*>(&Wt[(size_t)r1 * DIM + k0 + 32 + ch1 * 8]);
        }
        short8 af[4], bfr[4];
#pragma unroll
        for (int mi = 0; mi < 4; mi++)
            af[mi] = *reinterpret_cast<const short8*>(&Xs[cur][(wr * 64 + mi * 16 + l15) * 40 + l4 * 8]);
#pragma unroll
        for (int ni = 0; ni < 4; ni++)
            bfr[ni] = *reinterpret_cast<const short8*>(&Ws[cur][(wc * 64 + ni * 16 + l15) * 40 + l4 * 8]);
#pragma unroll
        for (int mi = 0; mi < 4; mi++)
#pragma unroll
            for (int ni = 0; ni < 4; ni++)
                acc[mi][ni] = __builtin_amdgcn_mfma_f32_16x16x32_bf16(af[mi], bfr[ni], acc[mi][ni], 0, 0, 0);
        if (more) {
            *reinterpret_cast<short8*>(&Xs[cur ^ 1][r0 * 40 + ch0 * 8]) = nx0;
            *reinterpret_cast<short8*>(&Xs[cur ^ 1][r1 * 40 + ch1 * 8]) = nx1;
            *reinterpret_cast<short8*>(&Ws[cur ^ 1][r0 * 40 + ch0 * 8]) = nw0;
            *reinterpret_cast<short8*>(&Ws[cur ^ 1][r1 * 40 + ch1 * 8]) = nw1;
        }
        __syncthreads();
        cur ^= 1;
    }

#pragma unroll
    for (int mi = 0; mi < 4; mi++) {
#pragma unroll
        for (int ni = 0; ni < 4; ni++) {
            int n = n0 + wc * 64 + ni * 16 + l15;
            float bv = bias[n];
            int h = n >> 6, d = n & 63;
#pragma unroll
            for (int j = 0; j < 4; j++) {
                int m = m0 + wr * 64 + mi * 16 + l4 * 4 + j;
                float val = acc[mi][ni][j] + bv;
                int b = m >> 11, s = m & 2047;
                if (proj == 0)
                    Qh[((size_t)(b * NH + h) * SEQ + s) * DK + d] = __float2bfloat16(val * 0.125f);
                else if (proj == 1)
                    Kh[((size_t)(b * NH + h) * SEQ + s) * DK + d] = __float2bfloat16(val);
                else
                    Vt[((size_t)(b * NH + h) * DK + d) * SEQ + s] = __float2bfloat16(val);
            }
        }
    }
}

// ---------------- O projection GEMM (unchanged) ----------------
__global__ __launch_bounds__(256) void o_gemm_kernel(
    const bf16* __restrict__ X, const bf16* __restrict__ Wt,
    const float* __restrict__ bias, float* __restrict__ out)
{
    __shared__ __align__(16) bf16 Xs[2][64 * 40];
    __shared__ __align__(16) bf16 Ws[2][128 * 40];
    const int tid = threadIdx.x;
    const int w = tid >> 6, l = tid & 63;
    const int l15 = l & 15, l4 = l >> 4;
    const int m0 = blockIdx.x * 64, n0 = blockIdx.y * 128;
    const int wr = w >> 1, wc = w & 1;
    f32x4 acc[2][4] = {};

    const int xr = tid >> 2, xc = tid & 3;
    const int c0 = tid, c1 = 256 + tid;
    const int wr0 = c0 >> 2, wc0 = c0 & 3;
    const int wr1 = c1 >> 2, wc1 = c1 & 3;
    const bf16* Xp = X + (size_t)m0 * DIM;
    const bf16* Wp = Wt + (size_t)n0 * DIM;

    short8 x0 = *reinterpret_cast<const short8*>(&Xp[(size_t)xr * DIM + xc * 8]);
    short8 w0 = *reinterpret_cast<const short8*>(&Wp[(size_t)wr0 * DIM + wc0 * 8]);
    short8 w1 = *reinterpret_cast<const short8*>(&Wp[(size_t)wr1 * DIM + wc1 * 8]);
    *reinterpret_cast<short8*>(&Xs[0][xr * 40 + xc * 8]) = x0;
    *reinterpret_cast<short8*>(&Ws[0][wr0 * 40 + wc0 * 8]) = w0;
    *reinterpret_cast<short8*>(&Ws[0][wr1 * 40 + wc1 * 8]) = w1;
    __syncthreads();

    int cur = 0;
    for (int k0 = 0; k0 < DIM; k0 += 32) {
        const bool more = (k0 + 32) < DIM;
        short8 nx0, nw0, nw1;
        if (more) {
            nx0 = *reinterpret_cast<const short8*>(&Xp[(size_t)xr * DIM + k0 + 32 + xc * 8]);
            nw0 = *reinterpret_cast<const short8*>(&Wp[(size_t)wr0 * DIM + k0 + 32 + wc0 * 8]);
            nw1 = *reinterpret_cast<const short8*>(&Wp[(size_t)wr1 * DIM + k0 + 32 + wc1 * 8]);
        }
        short8 af[2], bfr[4];
#pragma unroll
        for (int mi = 0; mi < 2; mi++)
            af[mi] = *reinterpret_cast<const short8*>(&Xs[cur][(wr * 32 + mi * 16 + l15) * 40 + l4 * 8]);
#pragma unroll
        for (int ni = 0; ni < 4; ni++)
            bfr[ni] = *reinterpret_cast<const short8*>(&Ws[cur][(wc * 64 + ni * 16 + l15) * 40 + l4 * 8]);
#pragma unroll
        for (int mi = 0; mi < 2; mi++)
#pragma unroll
            for (int ni = 0; ni < 4; ni++)
                acc[mi][ni] = __builtin_amdgcn_mfma_f32_16x16x32_bf16(af[mi], bfr[ni], acc[mi][ni], 0, 0, 0);
        if (more) {
            *reinterpret_cast<short8*>(&Xs[cur ^ 1][xr * 40 + xc * 8]) = nx0;
            *reinterpret_cast<short8*>(&Ws[cur ^ 1][wr0 * 40 + wc0 * 8]) = nw0;
            *reinterpret_cast<short8*>(&Ws[cur ^ 1][wr1 * 40 + wc1 * 8]) = nw1;
        }
        __syncthreads();
        cur ^= 1;
    }

#pragma unroll
    for (int mi = 0; mi < 2; mi++) {
#pragma unroll
        for (int ni = 0; ni < 4; ni++) {
            int n = n0 + wc * 64 + ni * 16 + l15;
            float bv = bias[n];
#pragma unroll
            for (int j = 0; j < 4; j++) {
                int m = m0 + wr * 32 + mi * 16 + l4 * 4 + j;
                out[(size_t)m * DIM + n] = acc[mi][ni][j] + bv;
            }
        }
    }
}

// ---------------- fused flash attention, 32x32 MFMA version ----------------
// grid (16, 32), 256 threads = 4 waves, 32 q-rows/wave, KVBLK=64.
// C/D layout (m74/m101-verified): col = lane&31, row = (reg&3)+8*(reg>>2)+4*(lane>>5).
// A/B frags: row/col = lane&31, k = (lane>>5)*8 + j.
__global__ __launch_bounds__(256) void attn_kernel(
    const bf16* __restrict__ Qh, const bf16* __restrict__ Kh,
    const bf16* __restrict__ Vt, const int* __restrict__ mask,
    float* __restrict__ scores, bf16* __restrict__ attn_c)
{
    __shared__ __align__(16) bf16 Ks[2][64 * 72];   // [kv][dk]
    __shared__ __align__(16) bf16 Vs[2][64 * 72];   // [dk][kv]
    __shared__ __align__(16) bf16 Ps[128 * 72];     // [q][kv]
    const int tid = threadIdx.x;
    const int w = tid >> 6, l = tid & 63;
    const int l31 = l & 31, l5 = l >> 5;
    const int bh = blockIdx.y;
    const int b = bh >> 4, h = bh & 15;
    const int q0 = blockIdx.x * 128;
    const size_t head = (size_t)bh * SEQ * DK;

    // staging decode: 512 16B-chunks per 64x64 tile, 2/thread (8 chunks per 128B row)
    const int c0 = tid, c1 = 256 + tid;
    const int kr0 = c0 >> 3, kc0 = c0 & 7;
    const int kr1 = c1 >> 3, kc1 = c1 & 7;

    // Q fragments (pre-scaled by 1/8): A row = l31, k = kb*16 + l5*8 + j
    short8 aq[4];
#pragma unroll
    for (int kb = 0; kb < 4; kb++)
        aq[kb] = *reinterpret_cast<const short8*>(
            &Qh[head + (size_t)(q0 + w * 32 + l31) * DK + kb * 16 + l5 * 8]);

    // stage kv tile 0
    {
        short8 k0v = *reinterpret_cast<const short8*>(&Kh[head + (size_t)kr0 * DK + kc0 * 8]);
        short8 k1v = *reinterpret_cast<const short8*>(&Kh[head + (size_t)kr1 * DK + kc1 * 8]);
        short8 v0v = *reinterpret_cast<const short8*>(&Vt[head + (size_t)kr0 * SEQ + kc0 * 8]);
        short8 v1v = *reinterpret_cast<const short8*>(&Vt[head + (size_t)kr1 * SEQ + kc1 * 8]);
        *reinterpret_cast<short8*>(&Ks[0][kr0 * 72 + kc0 * 8]) = k0v;
        *reinterpret_cast<short8*>(&Ks[0][kr1 * 72 + kc1 * 8]) = k1v;
        *reinterpret_cast<short8*>(&Vs[0][kr0 * 72 + kc0 * 8]) = v0v;
        *reinterpret_cast<short8*>(&Vs[0][kr1 * 72 + kc1 * 8]) = v1v;
    }
    __syncthreads();

    f32x16 o0 = {}, o1 = {};
    float mrun[16], lrun[16];
#pragma unroll
    for (int r = 0; r < 16; r++) { mrun[r] = -INFINITY; lrun[r] = 0.f; }

    const int* mrow = mask + b * SEQ;
    float* sp = scores + ((size_t)bh * SEQ + q0 + w * 32 + 4 * l5) * SEQ + l31;

    int cur = 0;
    for (int t = 0; t < SEQ / 64; t++) {
        const int kv0 = t * 64;
        const bool more = t < (SEQ / 64 - 1);
        short8 nk0, nk1, nv0, nv1;
        if (more) {
            nk0 = *reinterpret_cast<const short8*>(&Kh[head + (size_t)(kv0 + 64 + kr0) * DK + kc0 * 8]);
            nk1 = *reinterpret_cast<const short8*>(&Kh[head + (size_t)(kv0 + 64 + kr1) * DK + kc1 * 8]);
            nv0 = *reinterpret_cast<const short8*>(&Vt[head + (size_t)kr0 * SEQ + kv0 + 64 + kc0 * 8]);
            nv1 = *reinterpret_cast<const short8*>(&Vt[head + (size_t)kr1 * SEQ + kv0 + 64 + kc1 * 8]);
        }

        // S = Q K^T: two 32x32 output frags (kv groups f=0,1), 4 mfma each
        f32x16 s0 = {}, s1 = {};
#pragma unroll
        for (int kb = 0; kb < 4; kb++) {
            short8 bk0 = *reinterpret_cast<const short8*>(&Ks[cur][l31 * 72 + kb * 16 + l5 * 8]);
            short8 bk1 = *reinterpret_cast<const short8*>(&Ks[cur][(32 + l31) * 72 + kb * 16 + l5 * 8]);
            s0 = __builtin_amdgcn_mfma_f32_32x32x16_bf16(aq[kb], bk0, s0, 0, 0, 0);
            s1 = __builtin_amdgcn_mfma_f32_32x32x16_bf16(aq[kb], bk1, s1, 0, 0, 0);
        }

        // mask (L2-hot scalar loads)
        int mk0 = mrow[kv0 + l31];
        int mk1 = mrow[kv0 + 32 + l31];
        if (mk0 == 0) {
#pragma unroll
            for (int r = 0; r < 16; r++) s0[r] = NEG_INF_F;
        }
        if (mk1 == 0) {
#pragma unroll
            for (int r = 0; r < 16; r++) s1[r] = NEG_INF_F;
        }

        // write masked raw scores: per store, lanes 0-31 cover 128B contiguous
        {
            float* spt = sp + kv0;
#pragma unroll
            for (int r = 0; r < 16; r++) {
                size_t off = (size_t)((r & 3) + 8 * (r >> 2)) * SEQ;
                spt[off] = s0[r];
                spt[off + 32] = s1[r];
            }
        }

        // online softmax: row max (32-lane reduce), exp, deferred per-lane sum
#pragma unroll
        for (int r = 0; r < 16; r++) {
            float mx = fmaxf(s0[r], s1[r]);
#pragma unroll
            for (int d = 1; d < 32; d <<= 1) mx = fmaxf(mx, __shfl_xor(mx, d));
            if (mx > mrun[r]) {
                float fac = __expf(mrun[r] - mx);
                lrun[r] *= fac;
                o0[r] *= fac;
                o1[r] *= fac;
                mrun[r] = mx;
            }
            float p0 = __expf(s0[r] - mrun[r]);
            float p1 = __expf(s1[r] - mrun[r]);
            lrun[r] += p0 + p1;
            s0[r] = p0;
            s1[r] = p1;
        }

        // P -> LDS bf16 (wave-local rows; 32 lanes write 64B contiguous)
        {
            int prow = w * 32 + 4 * l5;
#pragma unroll
            for (int r = 0; r < 16; r++) {
                int ro = prow + (r & 3) + 8 * (r >> 2);
                Ps[ro * 72 + l31] = __float2bfloat16(s0[r]);
                Ps[ro * 72 + 32 + l31] = __float2bfloat16(s1[r]);
            }
        }

        // O += P V: A = P (row=q=l31, k=kv), B = V^T (col=dk=l31, k=kv)
#pragma unroll
        for (int kb = 0; kb < 4; kb++) {
            short8 pa = *reinterpret_cast<const short8*>(&Ps[(w * 32 + l31) * 72 + kb * 16 + l5 * 8]);
            short8 vb0 = *reinterpret_cast<const short8*>(&Vs[cur][l31 * 72 + kb * 16 + l5 * 8]);
            short8 vb1 = *reinterpret_cast<const short8*>(&Vs[cur][(32 + l31) * 72 + kb * 16 + l5 * 8]);
            o0 = __builtin_amdgcn_mfma_f32_32x32x16_bf16(pa, vb0, o0, 0, 0, 0);
            o1 = __builtin_amdgcn_mfma_f32_32x32x16_bf16(pa, vb1, o1, 0, 0, 0);
        }

        if (more) {
            *reinterpret_cast<short8*>(&Ks[cur ^ 1][kr0 * 72 + kc0 * 8]) = nk0;
            *reinterpret_cast<short8*>(&Ks[cur ^ 1][kr1 * 72 + kc1 * 8]) = nk1;
            *reinterpret_cast<short8*>(&Vs[cur ^ 1][kr0 * 72 + kc0 * 8]) = nv0;
            *reinterpret_cast<short8*>(&Vs[cur ^ 1][kr1 * 72 + kc1 * 8]) = nv1;
        }
        __syncthreads();
        cur ^= 1;
    }

    // epilogue: reduce deferred row-sums, normalize, write concat layout
#pragma unroll
    for (int r = 0; r < 16; r++) {
        float ls = lrun[r];
#pragma unroll
        for (int d = 1; d < 32; d <<= 1) ls += __shfl_xor(ls, d);
        float inv = 1.f / ls;
        int s = q0 + w * 32 + 4 * l5 + (r & 3) + 8 * (r >> 2);
        bf16* op = &attn_c[((size_t)(b * SEQ + s)) * DIM + h * DK];
        op[l31] = __float2bfloat16(o0[r] * inv);
        op[32 + l31] = __float2bfloat16(o1[r] * inv);
    }
}

extern "C" void kernel_launch(void* const* d_in, const int* in_sizes, int n_in,
                              void* d_out, int out_size, void* d_ws, size_t ws_size,
                              hipStream_t stream)
{
    const float* q  = (const float*)d_in[0];
    const float* k  = (const float*)d_in[1];
    const float* v  = (const float*)d_in[2];
    const int*  msk = (const int*)d_in[3];
    const float* Wq = (const float*)d_in[4];
    const float* bq = (const float*)d_in[5];
    const float* Wk = (const float*)d_in[6];
    const float* bk = (const float*)d_in[7];
    const float* Wv = (const float*)d_in[8];
    const float* bv = (const float*)d_in[9];
    const float* Wo = (const float*)d_in[10];
    const float* bo = (const float*)d_in[11];

    const size_t MB = 1ull << 20;
    char* ws = (char*)d_ws;
    bf16* qb  = (bf16*)(ws + 0 * MB);
    bf16* kb  = (bf16*)(ws + 8 * MB);
    bf16* vb  = (bf16*)(ws + 16 * MB);
    bf16* Wqt = (bf16*)(ws + 24 * MB);
    bf16* Wkt = (bf16*)(ws + 26 * MB);
    bf16* Wvt = (bf16*)(ws + 28 * MB);
    bf16* Wot = (bf16*)(ws + 30 * MB);
    bf16* QhD = (bf16*)(ws + 32 * MB);
    bf16* KhD = (bf16*)(ws + 40 * MB);
    bf16* VtD = (bf16*)(ws + 48 * MB);
    bf16* att = (bf16*)(ws + 56 * MB);

    float* out = (float*)d_out;
    float* scores = out + (size_t)4096 * 1024;

    cvt_all_kernel<<<3 * 4096, 256, 0, stream>>>(q, k, v, qb, kb, vb);
    transpose_cvt_kernel<<<dim3(32, 32, 4), dim3(32, 8), 0, stream>>>(
        Wq, Wk, Wv, Wo, Wqt, Wkt, Wvt, Wot);

    qkv_gemm_kernel<<<dim3(32, 24), 256, 0, stream>>>(qb, kb, vb, Wqt, bq, bk, bv, QhD, KhD, VtD);

    attn_kernel<<<dim3(16, 32), 256, 0, stream>>>(QhD, KhD, VtD, msk, scores, att);

    o_gemm_kernel<<<dim3(64, 8), 256, 0, stream>>>(att, Wot, bo, out);
}

// Round 6
// 240.244 us; speedup vs baseline: 1.3522x; 1.3522x over previous
//
#include <hip/hip_runtime.h>
#include <hip/hip_bf16.h>

typedef __attribute__((ext_vector_type(8))) short short8;
typedef __attribute__((ext_vector_type(4))) float f32x4;
typedef __hip_bfloat16 bf16;

#define NH 16
#define DK 64
#define SEQ 2048
#define DIM 1024
#define NEG_INF_F (-1.0e9f)

static __device__ __forceinline__ unsigned short f2bf_bits(float f) {
    bf16 t = __float2bfloat16(f);
    return *reinterpret_cast<unsigned short*>(&t);
}

// ---------------- fused convert f32 -> bf16 for q,k,v ----------------
__global__ void cvt_all_kernel(const float* __restrict__ q, const float* __restrict__ k,
                               const float* __restrict__ v, bf16* __restrict__ qb,
                               bf16* __restrict__ kb, bf16* __restrict__ vb) {
    const int N4 = 2 * SEQ * DIM / 4;
    int i = blockIdx.x * blockDim.x + threadIdx.x;
    int sel = i / N4, j = i - sel * N4;
    const float* in = (sel == 0) ? q : (sel == 1) ? k : v;
    bf16* out = (sel == 0) ? qb : (sel == 1) ? kb : vb;
    float4 x = reinterpret_cast<const float4*>(in)[j];
    ushort4 u;
    u.x = f2bf_bits(x.x);
    u.y = f2bf_bits(x.y);
    u.z = f2bf_bits(x.z);
    u.w = f2bf_bits(x.w);
    reinterpret_cast<ushort4*>(out)[j] = u;
}

// ---------------- fused W (K x N) f32 -> Wt (N x K) bf16 for 4 weights ----------------
__global__ void transpose_cvt_kernel(const float* __restrict__ Wq, const float* __restrict__ Wk,
                                     const float* __restrict__ Wv, const float* __restrict__ Wo,
                                     bf16* __restrict__ Wqt, bf16* __restrict__ Wkt,
                                     bf16* __restrict__ Wvt, bf16* __restrict__ Wot) {
    __shared__ float t[32][33];
    const int z = blockIdx.z;
    const float* W = (z == 0) ? Wq : (z == 1) ? Wk : (z == 2) ? Wv : Wo;
    bf16* Wt = (z == 0) ? Wqt : (z == 1) ? Wkt : (z == 2) ? Wvt : Wot;
    int n0 = blockIdx.x * 32, k0 = blockIdx.y * 32;
    int tx = threadIdx.x, ty = threadIdx.y;
#pragma unroll
    for (int i = 0; i < 4; i++)
        t[ty + i * 8][tx] = W[(size_t)(k0 + ty + i * 8) * DIM + n0 + tx];
    __syncthreads();
#pragma unroll
    for (int i = 0; i < 4; i++)
        Wt[(size_t)(n0 + ty + i * 8) * DIM + k0 + tx] = __float2bfloat16(t[tx][ty + i * 8]);
}

// ---------------- fused QKV projection GEMM ----------------
// 1D grid 768, n-fastest ordering + bijective XCD-chunk swizzle:
// each XCD chunk (96 blocks) = 12 m-tiles x 8 n-tiles of one proj
// -> L2 working set: 12 x 256KB X + 2MB W.
__global__ __launch_bounds__(256) void qkv_gemm_kernel(
    const bf16* __restrict__ qb, const bf16* __restrict__ kb, const bf16* __restrict__ vb,
    const bf16* __restrict__ Wcat,
    const float* __restrict__ bq, const float* __restrict__ bk, const float* __restrict__ bv,
    bf16* __restrict__ Qh, bf16* __restrict__ Kh, bf16* __restrict__ Vt)
{
    __shared__ __align__(16) bf16 Xs[2][128 * 40];
    __shared__ __align__(16) bf16 Ws[2][128 * 40];
    const int tid = threadIdx.x;
    const int w = tid >> 6, l = tid & 63;
    const int l15 = l & 15, l4 = l >> 4;
    const int lin = blockIdx.x;                 // 768 = 8 XCD x 96
    const int swz = (lin & 7) * 96 + (lin >> 3);
    const int proj = swz >> 8;                  // /256
    const int rem = swz & 255;
    const int m0 = (rem >> 3) * 128;            // 32 m-tiles
    const int n0 = (rem & 7) * 128;             // 8 n-tiles
    const bf16* X = (proj == 0) ? qb : (proj == 1) ? kb : vb;
    const bf16* Wt = Wcat + (size_t)proj * DIM * DIM + (size_t)n0 * DIM;
    const float* bias = (proj == 0) ? bq : (proj == 1) ? bk : bv;
    const int wr = w >> 1, wc = w & 1;
    f32x4 acc[4][4] = {};

    const int c0 = tid, c1 = 256 + tid;
    const int r0 = c0 >> 2, ch0 = c0 & 3;
    const int r1 = c1 >> 2, ch1 = c1 & 3;
    const bf16* Xp = X + (size_t)m0 * DIM;

    short8 x0 = *reinterpret_cast<const short8*>(&Xp[(size_t)r0 * DIM + ch0 * 8]);
    short8 x1 = *reinterpret_cast<const short8*>(&Xp[(size_t)r1 * DIM + ch1 * 8]);
    short8 w0 = *reinterpret_cast<const short8*>(&Wt[(size_t)r0 * DIM + ch0 * 8]);
    short8 w1 = *reinterpret_cast<const short8*>(&Wt[(size_t)r1 * DIM + ch1 * 8]);
    *reinterpret_cast<short8*>(&Xs[0][r0 * 40 + ch0 * 8]) = x0;
    *reinterpret_cast<short8*>(&Xs[0][r1 * 40 + ch1 * 8]) = x1;
    *reinterpret_cast<short8*>(&Ws[0][r0 * 40 + ch0 * 8]) = w0;
    *reinterpret_cast<short8*>(&Ws[0][r1 * 40 + ch1 * 8]) = w1;
    __syncthreads();

    int cur = 0;
    for (int k0 = 0; k0 < DIM; k0 += 32) {
        const bool more = (k0 + 32) < DIM;
        short8 nx0, nx1, nw0, nw1;
        if (more) {
            nx0 = *reinterpret_cast<const short8*>(&Xp[(size_t)r0 * DIM + k0 + 32 + ch0 * 8]);
            nx1 = *reinterpret_cast<const short8*>(&Xp[(size_t)r1 * DIM + k0 + 32 + ch1 * 8]);
            nw0 = *reinterpret_cast<const short8*>(&Wt[(size_t)r0 * DIM + k0 + 32 + ch0 * 8]);
            nw1 = *reinterpret_cast<const short8*>(&Wt[(size_t)r1 * DIM + k0 + 32 + ch1 * 8]);
        }
        short8 af[4], bfr[4];
#pragma unroll
        for (int mi = 0; mi < 4; mi++)
            af[mi] = *reinterpret_cast<const short8*>(&Xs[cur][(wr * 64 + mi * 16 + l15) * 40 + l4 * 8]);
#pragma unroll
        for (int ni = 0; ni < 4; ni++)
            bfr[ni] = *reinterpret_cast<const short8*>(&Ws[cur][(wc * 64 + ni * 16 + l15) * 40 + l4 * 8]);
#pragma unroll
        for (int mi = 0; mi < 4; mi++)
#pragma unroll
            for (int ni = 0; ni < 4; ni++)
                acc[mi][ni] = __builtin_amdgcn_mfma_f32_16x16x32_bf16(af[mi], bfr[ni], acc[mi][ni], 0, 0, 0);
        if (more) {
            *reinterpret_cast<short8*>(&Xs[cur ^ 1][r0 * 40 + ch0 * 8]) = nx0;
            *reinterpret_cast<short8*>(&Xs[cur ^ 1][r1 * 40 + ch1 * 8]) = nx1;
            *reinterpret_cast<short8*>(&Ws[cur ^ 1][r0 * 40 + ch0 * 8]) = nw0;
            *reinterpret_cast<short8*>(&Ws[cur ^ 1][r1 * 40 + ch1 * 8]) = nw1;
        }
        __syncthreads();
        cur ^= 1;
    }

#pragma unroll
    for (int mi = 0; mi < 4; mi++) {
#pragma unroll
        for (int ni = 0; ni < 4; ni++) {
            int n = n0 + wc * 64 + ni * 16 + l15;
            float bv = bias[n];
            int h = n >> 6, d = n & 63;
#pragma unroll
            for (int j = 0; j < 4; j++) {
                int m = m0 + wr * 64 + mi * 16 + l4 * 4 + j;
                float val = acc[mi][ni][j] + bv;
                int b = m >> 11, s = m & 2047;
                if (proj == 0)
                    Qh[((size_t)(b * NH + h) * SEQ + s) * DK + d] = __float2bfloat16(val * 0.125f);
                else if (proj == 1)
                    Kh[((size_t)(b * NH + h) * SEQ + s) * DK + d] = __float2bfloat16(val);
                else
                    Vt[((size_t)(b * NH + h) * DK + d) * SEQ + s] = __float2bfloat16(val);
            }
        }
    }
}

// ---------------- O projection GEMM ----------------
// 1D grid 512, n-fastest + XCD-chunk swizzle: chunk = 8 m-tiles x 8 n
// -> L2 set: 1MB X + 2MB W.
__global__ __launch_bounds__(256) void o_gemm_kernel(
    const bf16* __restrict__ X, const bf16* __restrict__ Wt,
    const float* __restrict__ bias, float* __restrict__ out)
{
    __shared__ __align__(16) bf16 Xs[2][64 * 40];
    __shared__ __align__(16) bf16 Ws[2][128 * 40];
    const int tid = threadIdx.x;
    const int w = tid >> 6, l = tid & 63;
    const int l15 = l & 15, l4 = l >> 4;
    const int lin = blockIdx.x;                 // 512 = 8 x 64
    const int swz = (lin & 7) * 64 + (lin >> 3);
    const int m0 = (swz >> 3) * 64;             // 64 m-tiles
    const int n0 = (swz & 7) * 128;             // 8 n-tiles
    const int wr = w >> 1, wc = w & 1;
    f32x4 acc[2][4] = {};

    const int xr = tid >> 2, xc = tid & 3;
    const int c0 = tid, c1 = 256 + tid;
    const int wr0 = c0 >> 2, wc0 = c0 & 3;
    const int wr1 = c1 >> 2, wc1 = c1 & 3;
    const bf16* Xp = X + (size_t)m0 * DIM;
    const bf16* Wp = Wt + (size_t)n0 * DIM;

    short8 x0 = *reinterpret_cast<const short8*>(&Xp[(size_t)xr * DIM + xc * 8]);
    short8 w0 = *reinterpret_cast<const short8*>(&Wp[(size_t)wr0 * DIM + wc0 * 8]);
    short8 w1 = *reinterpret_cast<const short8*>(&Wp[(size_t)wr1 * DIM + wc1 * 8]);
    *reinterpret_cast<short8*>(&Xs[0][xr * 40 + xc * 8]) = x0;
    *reinterpret_cast<short8*>(&Ws[0][wr0 * 40 + wc0 * 8]) = w0;
    *reinterpret_cast<short8*>(&Ws[0][wr1 * 40 + wc1 * 8]) = w1;
    __syncthreads();

    int cur = 0;
    for (int k0 = 0; k0 < DIM; k0 += 32) {
        const bool more = (k0 + 32) < DIM;
        short8 nx0, nw0, nw1;
        if (more) {
            nx0 = *reinterpret_cast<const short8*>(&Xp[(size_t)xr * DIM + k0 + 32 + xc * 8]);
            nw0 = *reinterpret_cast<const short8*>(&Wp[(size_t)wr0 * DIM + k0 + 32 + wc0 * 8]);
            nw1 = *reinterpret_cast<const short8*>(&Wp[(size_t)wr1 * DIM + k0 + 32 + wc1 * 8]);
        }
        short8 af[2], bfr[4];
#pragma unroll
        for (int mi = 0; mi < 2; mi++)
            af[mi] = *reinterpret_cast<const short8*>(&Xs[cur][(wr * 32 + mi * 16 + l15) * 40 + l4 * 8]);
#pragma unroll
        for (int ni = 0; ni < 4; ni++)
            bfr[ni] = *reinterpret_cast<const short8*>(&Ws[cur][(wc * 64 + ni * 16 + l15) * 40 + l4 * 8]);
#pragma unroll
        for (int mi = 0; mi < 2; mi++)
#pragma unroll
            for (int ni = 0; ni < 4; ni++)
                acc[mi][ni] = __builtin_amdgcn_mfma_f32_16x16x32_bf16(af[mi], bfr[ni], acc[mi][ni], 0, 0, 0);
        if (more) {
            *reinterpret_cast<short8*>(&Xs[cur ^ 1][xr * 40 + xc * 8]) = nx0;
            *reinterpret_cast<short8*>(&Ws[cur ^ 1][wr0 * 40 + wc0 * 8]) = nw0;
            *reinterpret_cast<short8*>(&Ws[cur ^ 1][wr1 * 40 + wc1 * 8]) = nw1;
        }
        __syncthreads();
        cur ^= 1;
    }

#pragma unroll
    for (int mi = 0; mi < 2; mi++) {
#pragma unroll
        for (int ni = 0; ni < 4; ni++) {
            int n = n0 + wc * 64 + ni * 16 + l15;
            float bv = bias[n];
#pragma unroll
            for (int j = 0; j < 4; j++) {
                int m = m0 + wr * 32 + mi * 16 + l4 * 4 + j;
                out[(size_t)m * DIM + n] = acc[mi][ni][j] + bv;
            }
        }
    }
}

// ---------------- fused flash attention (16x16 MFMA, round-4 structure) ----------------
// 1D grid 512 with XCD-chunk swizzle: each XCD gets 4 heads (2MB K/V, L2-resident).
// Nontemporal scores stores keep the 537MB stream from evicting K/V in L2.
__global__ __launch_bounds__(256) void attn_kernel(
    const bf16* __restrict__ Qh, const bf16* __restrict__ Kh,
    const bf16* __restrict__ Vt, const int* __restrict__ mask,
    float* __restrict__ scores, bf16* __restrict__ attn_c)
{
    __shared__ __align__(16) bf16 Ks[2][64 * 72];
    __shared__ __align__(16) bf16 Vs[2][64 * 72];
    __shared__ __align__(16) bf16 Ps[128 * 72];
    __shared__ int msk_s[SEQ];
    const int tid = threadIdx.x;
    const int w = tid >> 6, l = tid & 63;
    const int l15 = l & 15, l4 = l >> 4;
    const int lin = blockIdx.x;                 // 512 = 8 x 64
    const int swz = (lin & 7) * 64 + (lin >> 3);
    const int bh = swz >> 4;                    // 32 heads
    const int q0 = (swz & 15) * 128;            // 16 q-tiles
    const int b = bh >> 4, h = bh & 15;
    const size_t head = (size_t)bh * SEQ * DK;

    const int c0 = tid, c1 = 256 + tid;
    const int kr0 = c0 >> 3, kc0 = c0 & 7;
    const int kr1 = c1 >> 3, kc1 = c1 & 7;

    short8 aq[2][2];
#pragma unroll
    for (int mi = 0; mi < 2; mi++)
#pragma unroll
        for (int ks = 0; ks < 2; ks++)
            aq[mi][ks] = *reinterpret_cast<const short8*>(
                &Qh[head + (size_t)(q0 + w * 32 + mi * 16 + l15) * DK + ks * 32 + l4 * 8]);

    {
        const int4* msrc = reinterpret_cast<const int4*>(mask + b * SEQ);
#pragma unroll
        for (int i = 0; i < 2; i++)
            reinterpret_cast<int4*>(msk_s)[i * 256 + tid] = msrc[i * 256 + tid];
        short8 k0v = *reinterpret_cast<const short8*>(&Kh[head + (size_t)kr0 * DK + kc0 * 8]);
        short8 k1v = *reinterpret_cast<const short8*>(&Kh[head + (size_t)kr1 * DK + kc1 * 8]);
        short8 v0v = *reinterpret_cast<const short8*>(&Vt[head + (size_t)kr0 * SEQ + kc0 * 8]);
        short8 v1v = *reinterpret_cast<const short8*>(&Vt[head + (size_t)kr1 * SEQ + kc1 * 8]);
        *reinterpret_cast<short8*>(&Ks[0][kr0 * 72 + kc0 * 8]) = k0v;
        *reinterpret_cast<short8*>(&Ks[0][kr1 * 72 + kc1 * 8]) = k1v;
        *reinterpret_cast<short8*>(&Vs[0][kr0 * 72 + kc0 * 8]) = v0v;
        *reinterpret_cast<short8*>(&Vs[0][kr1 * 72 + kc1 * 8]) = v1v;
    }
    __syncthreads();

    f32x4 oacc[2][4] = {};
    float mrun[2][4], lrun[2][4];   // lrun holds per-lane PARTIAL sums (reduced in epilogue)
#pragma unroll
    for (int mi = 0; mi < 2; mi++)
#pragma unroll
        for (int j = 0; j < 4; j++) { mrun[mi][j] = -INFINITY; lrun[mi][j] = 0.f; }

    int cur = 0;
    for (int t = 0; t < SEQ / 64; t++) {
        const int kv0 = t * 64;
        const bool more = t < (SEQ / 64 - 1);
        short8 nk0, nk1, nv0, nv1;
        if (more) {
            nk0 = *reinterpret_cast<const short8*>(&Kh[head + (size_t)(kv0 + 64 + kr0) * DK + kc0 * 8]);
            nk1 = *reinterpret_cast<const short8*>(&Kh[head + (size_t)(kv0 + 64 + kr1) * DK + kc1 * 8]);
            nv0 = *reinterpret_cast<const short8*>(&Vt[head + (size_t)kr0 * SEQ + kv0 + 64 + kc0 * 8]);
            nv1 = *reinterpret_cast<const short8*>(&Vt[head + (size_t)kr1 * SEQ + kv0 + 64 + kc1 * 8]);
        }

        // S = Q K^T
        f32x4 sacc[2][4] = {};
#pragma unroll
        for (int ks = 0; ks < 2; ks++) {
            short8 bk[4];
#pragma unroll
            for (int ni = 0; ni < 4; ni++)
                bk[ni] = *reinterpret_cast<const short8*>(&Ks[cur][(ni * 16 + l15) * 72 + ks * 32 + l4 * 8]);
#pragma unroll
            for (int mi = 0; mi < 2; mi++)
#pragma unroll
                for (int ni = 0; ni < 4; ni++)
                    sacc[mi][ni] = __builtin_amdgcn_mfma_f32_16x16x32_bf16(aq[mi][ks], bk[ni], sacc[mi][ni], 0, 0, 0);
        }

        // mask (LDS)
        int mk[4];
#pragma unroll
        for (int ni = 0; ni < 4; ni++) mk[ni] = msk_s[kv0 + ni * 16 + l15];
#pragma unroll
        for (int mi = 0; mi < 2; mi++)
#pragma unroll
            for (int ni = 0; ni < 4; ni++)
                if (mk[ni] == 0) {
#pragma unroll
                    for (int j = 0; j < 4; j++) sacc[mi][ni][j] = NEG_INF_F;
                }

        // masked raw scores -> d_out (nontemporal: write-once stream)
        {
            size_t base = ((size_t)bh * SEQ + q0 + w * 32) * SEQ + kv0;
#pragma unroll
            for (int mi = 0; mi < 2; mi++)
#pragma unroll
                for (int j = 0; j < 4; j++) {
                    size_t rb = base + (size_t)(mi * 16 + l4 * 4 + j) * SEQ;
#pragma unroll
                    for (int ni = 0; ni < 4; ni++)
                        __builtin_nontemporal_store(sacc[mi][ni][j], &scores[rb + ni * 16 + l15]);
                }
        }

        // online softmax; rescale only when max grows; sum deferred (per-lane partials)
#pragma unroll
        for (int mi = 0; mi < 2; mi++)
#pragma unroll
            for (int j = 0; j < 4; j++) {
                float mx = fmaxf(fmaxf(sacc[mi][0][j], sacc[mi][1][j]),
                                 fmaxf(sacc[mi][2][j], sacc[mi][3][j]));
#pragma unroll
                for (int d = 1; d < 16; d <<= 1) mx = fmaxf(mx, __shfl_xor(mx, d));
                if (mx > mrun[mi][j]) {
                    float fac = __expf(mrun[mi][j] - mx);
                    lrun[mi][j] *= fac;
#pragma unroll
                    for (int ni = 0; ni < 4; ni++) oacc[mi][ni][j] *= fac;
                    mrun[mi][j] = mx;
                }
                float mcur = mrun[mi][j];
                float ps = 0.f;
#pragma unroll
                for (int ni = 0; ni < 4; ni++) {
                    float p = __expf(sacc[mi][ni][j] - mcur);
                    sacc[mi][ni][j] = p;
                    ps += p;
                }
                lrun[mi][j] += ps;   // partial; 16-lane reduce happens once, in epilogue
            }

        // P -> LDS (wave-local rows)
#pragma unroll
        for (int mi = 0; mi < 2; mi++)
#pragma unroll
            for (int j = 0; j < 4; j++) {
                int r = w * 32 + mi * 16 + l4 * 4 + j;
#pragma unroll
                for (int ni = 0; ni < 4; ni++)
                    Ps[r * 72 + ni * 16 + l15] = __float2bfloat16(sacc[mi][ni][j]);
            }

        // O += P V
#pragma unroll
        for (int ks = 0; ks < 2; ks++) {
            short8 pa[2], vbf[4];
#pragma unroll
            for (int mi = 0; mi < 2; mi++)
                pa[mi] = *reinterpret_cast<const short8*>(&Ps[(w * 32 + mi * 16 + l15) * 72 + ks * 32 + l4 * 8]);
#pragma unroll
            for (int ni = 0; ni < 4; ni++)
                vbf[ni] = *reinterpret_cast<const short8*>(&Vs[cur][(ni * 16 + l15) * 72 + ks * 32 + l4 * 8]);
#pragma unroll
            for (int mi = 0; mi < 2; mi++)
#pragma unroll
                for (int ni = 0; ni < 4; ni++)
                    oacc[mi][ni] = __builtin_amdgcn_mfma_f32_16x16x32_bf16(pa[mi], vbf[ni], oacc[mi][ni], 0, 0, 0);
        }

        if (more) {
            *reinterpret_cast<short8*>(&Ks[cur ^ 1][kr0 * 72 + kc0 * 8]) = nk0;
            *reinterpret_cast<short8*>(&Ks[cur ^ 1][kr1 * 72 + kc1 * 8]) = nk1;
            *reinterpret_cast<short8*>(&Vs[cur ^ 1][kr0 * 72 + kc0 * 8]) = nv0;
            *reinterpret_cast<short8*>(&Vs[cur ^ 1][kr1 * 72 + kc1 * 8]) = nv1;
        }
        __syncthreads();
        cur ^= 1;
    }

    // epilogue: reduce deferred row-sums (16-lane groups), normalize, write concat layout
#pragma unroll
    for (int mi = 0; mi < 2; mi++)
#pragma unroll
        for (int j = 0; j < 4; j++) {
            float ls = lrun[mi][j];
#pragma unroll
            for (int d = 1; d < 16; d <<= 1) ls += __shfl_xor(ls, d);
            float inv = 1.f / ls;
            int s = q0 + w * 32 + mi * 16 + l4 * 4 + j;
#pragma unroll
            for (int ni = 0; ni < 4; ni++)
                attn_c[((size_t)(b * SEQ + s)) * DIM + h * DK + ni * 16 + l15] =
                    __float2bfloat16(oacc[mi][ni][j] * inv);
        }
}

extern "C" void kernel_launch(void* const* d_in, const int* in_sizes, int n_in,
                              void* d_out, int out_size, void* d_ws, size_t ws_size,
                              hipStream_t stream)
{
    const float* q  = (const float*)d_in[0];
    const float* k  = (const float*)d_in[1];
    const float* v  = (const float*)d_in[2];
    const int*  msk = (const int*)d_in[3];
    const float* Wq = (const float*)d_in[4];
    const float* bq = (const float*)d_in[5];
    const float* Wk = (const float*)d_in[6];
    const float* bk = (const float*)d_in[7];
    const float* Wv = (const float*)d_in[8];
    const float* bv = (const float*)d_in[9];
    const float* Wo = (const float*)d_in[10];
    const float* bo = (const float*)d_in[11];

    const size_t MB = 1ull << 20;
    char* ws = (char*)d_ws;
    bf16* qb  = (bf16*)(ws + 0 * MB);
    bf16* kb  = (bf16*)(ws + 8 * MB);
    bf16* vb  = (bf16*)(ws + 16 * MB);
    bf16* Wqt = (bf16*)(ws + 24 * MB);
    bf16* Wkt = (bf16*)(ws + 26 * MB);
    bf16* Wvt = (bf16*)(ws + 28 * MB);
    bf16* Wot = (bf16*)(ws + 30 * MB);
    bf16* QhD = (bf16*)(ws + 32 * MB);
    bf16* KhD = (bf16*)(ws + 40 * MB);
    bf16* VtD = (bf16*)(ws + 48 * MB);
    bf16* att = (bf16*)(ws + 56 * MB);

    float* out = (float*)d_out;
    float* scores = out + (size_t)4096 * 1024;

    cvt_all_kernel<<<3 * 4096, 256, 0, stream>>>(q, k, v, qb, kb, vb);
    transpose_cvt_kernel<<<dim3(32, 32, 4), dim3(32, 8), 0, stream>>>(
        Wq, Wk, Wv, Wo, Wqt, Wkt, Wvt, Wot);

    qkv_gemm_kernel<<<768, 256, 0, stream>>>(qb, kb, vb, Wqt, bq, bk, bv, QhD, KhD, VtD);

    attn_kernel<<<512, 256, 0, stream>>>(QhD, KhD, VtD, msk, scores, att);

    o_gemm_kernel<<<512, 256, 0, stream>>>(att, Wot, bo, out);
}